// Round 1
// baseline (296.615 us; speedup 1.0000x reference)
//
#include <hip/hip_runtime.h>
#include <hip/hip_bf16.h>
#include <math.h>

// ---- problem constants (fixed by setup_inputs) ----
constexpr int B   = 4;
constexpr int S   = 4096;
constexpr int D   = 64;
constexpr int NH  = 8;        // hash rounds
constexpr int NB  = 64;       // buckets per hash
constexpr int NBT = 512;      // total buckets = NH*NB
constexpr int NI  = NH * S;   // items per batch = 32768
constexpr int NCH = 512;      // chunks per batch (of 64)
constexpr int CHB = 128;      // sort chunks per batch (of 256)

// ============================================================
// K1: LSH hashing — buckets[b, h*S+t] = argmax([rot,-rot]) + h*64
// ============================================================
__global__ void k_hash(const float* __restrict__ q, const float* __restrict__ rot,
                       int* __restrict__ buckets) {
    // grid: B*NH*(S/256) = 512 blocks, 256 threads
    int blk = blockIdx.x;
    int tch = blk & 15;
    int h   = (blk >> 4) & 7;
    int b   = blk >> 7;
    __shared__ float rs[D * 32];
    for (int i = threadIdx.x; i < D * 32; i += 256) {
        int d = i >> 5, n = i & 31;
        rs[i] = rot[(d * NH + h) * 32 + n];
    }
    __syncthreads();
    int t = tch * 256 + threadIdx.x;
    const float* qp = q + ((size_t)b * S + t) * D;
    float qr[D];
#pragma unroll
    for (int d0 = 0; d0 < D; d0 += 4) {
        float4 v4 = *(const float4*)(qp + d0);
        qr[d0] = v4.x; qr[d0 + 1] = v4.y; qr[d0 + 2] = v4.z; qr[d0 + 3] = v4.w;
    }
    float bp = -3.402823466e38f, bn = -3.402823466e38f;
    int ip = 0, ineg = 0;
    for (int n = 0; n < 32; ++n) {
        float acc = 0.f;
#pragma unroll
        for (int d = 0; d < D; ++d) acc += qr[d] * rs[d * 32 + n];
        if (acc > bp)  { bp = acc;  ip = n; }
        if (-acc > bn) { bn = -acc; ineg = n; }
    }
    int bi = (bn > bp) ? (ineg + 32) : ip;   // tie -> positive half (earlier index)
    buckets[b * NI + h * S + t] = bi + h * NB;
}

// ============================================================
// K1b: normalize k rows
// ============================================================
__global__ void k_knorm(const float* __restrict__ k, float* __restrict__ kn) {
    // grid: B*S/4 blocks, 256 threads (4 rows x 64 lanes)
    int row  = blockIdx.x * 4 + (threadIdx.x >> 6);
    int lane = threadIdx.x & 63;
    float v = k[(size_t)row * D + lane];
    float ss = v * v;
#pragma unroll
    for (int m = 1; m < 64; m <<= 1) ss += __shfl_xor(ss, m, 64);
    kn[(size_t)row * D + lane] = v / sqrtf(ss);
}

// ============================================================
// K2: per-chunk bucket histograms (chunks of 256 items)
// ============================================================
__global__ void k_hist(const int* __restrict__ buckets, int* __restrict__ counts) {
    // grid: B*CHB blocks, 256 threads
    int b = blockIdx.x >> 7, c = blockIdx.x & 127;
    __shared__ int hist[NBT];
    hist[threadIdx.x] = 0; hist[threadIdx.x + 256] = 0;
    __syncthreads();
    int bkt = buckets[b * NI + c * 256 + threadIdx.x];
    atomicAdd(&hist[bkt], 1);
    __syncthreads();
    counts[(b * CHB + c) * NBT + threadIdx.x]       = hist[threadIdx.x];
    counts[(b * CHB + c) * NBT + threadIdx.x + 256] = hist[threadIdx.x + 256];
}

// ============================================================
// K3: per-batch scan: counts -> per-chunk exclusive prefix (in place),
//     base[bkt] = exclusive scan of bucket totals
// ============================================================
__global__ void k_scan(int* __restrict__ counts, int* __restrict__ base) {
    // grid: B blocks, 512 threads
    int b = blockIdx.x, bkt = threadIdx.x;
    int run = 0;
    for (int c = 0; c < CHB; ++c) {
        int idx = (b * CHB + c) * NBT + bkt;
        int v = counts[idx];
        counts[idx] = run;       // prefix before chunk c
        run += v;
    }
    __shared__ int bufA[NBT], bufB[NBT];
    bufA[bkt] = run;
    __syncthreads();
    int* src = bufA; int* dst = bufB;
    for (int off = 1; off < NBT; off <<= 1) {
        int x = src[bkt] + ((bkt >= off) ? src[bkt - off] : 0);
        dst[bkt] = x;
        __syncthreads();
        int* tsw = src; src = dst; dst = tsw;
    }
    base[b * NBT + bkt] = src[bkt] - run;  // exclusive
}

// ============================================================
// K4: stable scatter — sorted arrays + inverse permutation
// ============================================================
__global__ void k_scatter(const int* __restrict__ buckets, const int* __restrict__ counts,
                          const int* __restrict__ base, int* __restrict__ stflat,
                          int* __restrict__ sbkt, int* __restrict__ undo) {
    // grid: B*CHB blocks, 256 threads
    int b = blockIdx.x >> 7, c = blockIdx.x & 127;
    __shared__ int bk_s[256];
    int i_loc  = threadIdx.x;
    int i_flat = c * 256 + i_loc;
    int bkt = buckets[b * NI + i_flat];
    bk_s[i_loc] = bkt;
    __syncthreads();
    int rank = 0;
    for (int j = 0; j < 256; ++j) {
        int v = bk_s[j];                 // uniform address -> broadcast
        rank += (j < i_loc && v == bkt);
    }
    int pos = base[b * NBT + bkt] + counts[(b * CHB + c) * NBT + bkt] + rank;
    stflat[b * NI + pos] = i_flat;
    sbkt[b * NI + pos]   = bkt;
    undo[b * NI + i_flat] = pos;
}

// ============================================================
// K5: loc1[b,i] = bucket*512 + chunk-in-sorted-order
// ============================================================
__global__ void k_loc(const int* __restrict__ buckets, const int* __restrict__ undo,
                      int* __restrict__ loc1) {
    int idx = blockIdx.x * 256 + threadIdx.x;   // B*NI total
    loc1[idx] = buckets[idx] * NCH + (undo[idx] >> 6);
}

// ============================================================
// K6: chunked attention (64 q rows x 128 keys, d=64)
// ============================================================
__global__ __launch_bounds__(512)
void k_attn(const float* __restrict__ q, const float* __restrict__ kn,
            const float* __restrict__ v, const int* __restrict__ stflat,
            const int* __restrict__ sbkt, const int* __restrict__ loc1,
            float* __restrict__ so, float* __restrict__ slog) {
    int n = blockIdx.x & 511, b = blockIdx.x >> 9;
    __shared__ float qs[64 * 65];
    __shared__ float ks[128 * 65];
    __shared__ float vs[128 * 65];
    __shared__ float ps[64 * 129];
    __shared__ int tq[64], bqs[64], lq[64 * 9];
    __shared__ int tk[128], bks[128], lk1[128 * 9], lk2[128 * 9];
    int tid = threadIdx.x;

    // ---- metadata ----
    if (tid < 64) {
        int p  = n * 64 + tid;
        int fl = stflat[b * NI + p];
        int t  = fl & (S - 1);
        tq[tid]  = t;
        bqs[tid] = sbkt[b * NI + p];
#pragma unroll
        for (int h = 0; h < NH; ++h) lq[tid * 9 + h] = loc1[b * NI + (h << 12) + t];
    } else if (tid < 192) {
        int z  = tid - 64;
        int nn = (z < 64) ? n : ((n + 511) & 511);
        int p  = nn * 64 + (z & 63);
        int fl = stflat[b * NI + p];
        int t  = fl & (S - 1);
        tk[z]  = t;
        bks[z] = sbkt[b * NI + p];
#pragma unroll
        for (int h = 0; h < NH; ++h) {
            int l1 = loc1[b * NI + (h << 12) + t];
            lk1[z * 9 + h] = l1;
            lk2[z * 9 + h] = (l1 & ~511) | ((l1 + 1) & 511);
        }
    }
    __syncthreads();

    // ---- stage rows into LDS ----
    const size_t gb = (size_t)b * S * D;
    for (int idx = tid; idx < 64 * 16; idx += 512) {
        int row = idx >> 4, c4 = (idx & 15) * 4;
        float4 val = *(const float4*)(q + gb + (size_t)tq[row] * D + c4);
        float* dst = &qs[row * 65 + c4];
        dst[0] = val.x; dst[1] = val.y; dst[2] = val.z; dst[3] = val.w;
    }
    for (int idx = tid; idx < 128 * 16; idx += 512) {
        int row = idx >> 4, c4 = (idx & 15) * 4;
        int t = tk[row];
        float4 kv = *(const float4*)(kn + gb + (size_t)t * D + c4);
        float* dst = &ks[row * 65 + c4];
        dst[0] = kv.x; dst[1] = kv.y; dst[2] = kv.z; dst[3] = kv.w;
        float4 vv = *(const float4*)(v + gb + (size_t)t * D + c4);
        dst = &vs[row * 65 + c4];
        dst[0] = vv.x; dst[1] = vv.y; dst[2] = vv.z; dst[3] = vv.w;
    }
    __syncthreads();

    // ---- dots: thread owns 2 rows x 8 z (z interleaved by 16) ----
    int rb = tid >> 4, zb = tid & 15;
    int r0 = rb * 2;
    float acc[2][8];
#pragma unroll
    for (int i = 0; i < 2; ++i)
#pragma unroll
        for (int j = 0; j < 8; ++j) acc[i][j] = 0.f;
    for (int kk = 0; kk < 64; ++kk) {
        float q0 = qs[r0 * 65 + kk], q1 = qs[(r0 + 1) * 65 + kk];
#pragma unroll
        for (int zi = 0; zi < 8; ++zi) {
            float kv = ks[(zb + 16 * zi) * 65 + kk];
            acc[0][zi] += q0 * kv;
            acc[1][zi] += q1 * kv;
        }
    }

    // ---- masks + dup correction + softmax (per row, 16 lanes) ----
#pragma unroll
    for (int ri = 0; ri < 2; ++ri) {
        int r   = r0 + ri;
        int t_q = tq[r], b_q = bqs[r];
        float sv[8];
        float m = -3.402823466e38f;
#pragma unroll
        for (int zi = 0; zi < 8; ++zi) {
            int z = zb + 16 * zi;
            float s = acc[ri][zi] * 0.125f;
            if (t_q == tk[z]) s = -10000.0f;
            if (b_q != bks[z]) s = -3.402823466e38f;
            int dup = 0;
#pragma unroll
            for (int h = 0; h < NH; ++h) {
                int ql = lq[r * 9 + h];
                dup += (ql == lk1[z * 9 + h]) + (ql == lk2[z * 9 + h]);
            }
            s -= logf((float)dup + 1e-9f);
            sv[zi] = s;
            m = fmaxf(m, s);
        }
#pragma unroll
        for (int off = 1; off < 16; off <<= 1) m = fmaxf(m, __shfl_xor(m, off, 64));
        float sum = 0.f;
#pragma unroll
        for (int zi = 0; zi < 8; ++zi) sum += expf(sv[zi] - m);
#pragma unroll
        for (int off = 1; off < 16; off <<= 1) sum += __shfl_xor(sum, off, 64);
        float lse = m + logf(sum);
#pragma unroll
        for (int zi = 0; zi < 8; ++zi) ps[r * 129 + zb + 16 * zi] = expf(sv[zi] - lse);
        if (zb == 0) slog[b * NI + n * 64 + r] = lse;
    }
    __syncthreads();

    // ---- PV: thread owns (row, 8-wide d slice) ----
    int r = tid >> 3, ds = tid & 7, d0 = ds * 8;
    float o[8];
#pragma unroll
    for (int i = 0; i < 8; ++i) o[i] = 0.f;
    for (int z = 0; z < 128; ++z) {
        float p = ps[r * 129 + z];
#pragma unroll
        for (int di = 0; di < 8; ++di) o[di] += p * vs[z * 65 + d0 + di];
    }
    float* op = so + ((size_t)b * NI + n * 64 + r) * D + d0;
    *(float4*)op       = make_float4(o[0], o[1], o[2], o[3]);
    *(float4*)(op + 4) = make_float4(o[4], o[5], o[6], o[7]);
}

// ============================================================
// K7: unsort + combine across hash rounds
// ============================================================
__global__ void k_comb(const int* __restrict__ undo, const float* __restrict__ slog,
                       const float* __restrict__ so, float* __restrict__ out) {
    // grid: B*S/4 blocks, 256 threads (4 tokens x 64 lanes)
    int flatT = blockIdx.x * 4 + (threadIdx.x >> 6);
    int lane  = threadIdx.x & 63;
    int b = flatT >> 12, t = flatT & (S - 1);
    int ph[NH]; float lg[NH];
    float m = -3.402823466e38f;
#pragma unroll
    for (int h = 0; h < NH; ++h) {
        ph[h] = undo[b * NI + (h << 12) + t];
        lg[h] = slog[b * NI + ph[h]];
        m = fmaxf(m, lg[h]);
    }
    float sum = 0.f;
#pragma unroll
    for (int h = 0; h < NH; ++h) sum += expf(lg[h] - m);
    float lse2 = m + logf(sum);
    float o = 0.f;
#pragma unroll
    for (int h = 0; h < NH; ++h) {
        float w = expf(lg[h] - lse2);
        o += w * so[((size_t)b * NI + ph[h]) * D + lane];
    }
    out[(size_t)flatT * D + lane] = o;
}

// ============================================================
extern "C" void kernel_launch(void* const* d_in, const int* in_sizes, int n_in,
                              void* d_out, int out_size, void* d_ws, size_t ws_size,
                              hipStream_t stream) {
    const float* q   = (const float*)d_in[0];
    const float* k   = (const float*)d_in[1];
    const float* v   = (const float*)d_in[2];
    const float* rot = (const float*)d_in[3];
    float* out = (float*)d_out;

    char* ws = (char*)d_ws;
    size_t off = 0;
    auto alloc = [&](size_t bytes) -> void* {
        void* p = ws + off;
        off += (bytes + 255) & ~(size_t)255;
        return p;
    };
    float* kn      = (float*)alloc((size_t)B * S * D * 4);
    float* so      = (float*)alloc((size_t)B * NI * D * 4);
    float* slog    = (float*)alloc((size_t)B * NI * 4);
    int*   buckets = (int*)alloc((size_t)B * NI * 4);
    int*   counts  = (int*)alloc((size_t)B * CHB * NBT * 4);
    int*   base    = (int*)alloc((size_t)B * NBT * 4);
    int*   stflat  = (int*)alloc((size_t)B * NI * 4);
    int*   sbkt    = (int*)alloc((size_t)B * NI * 4);
    int*   undo    = (int*)alloc((size_t)B * NI * 4);
    int*   loc1    = (int*)alloc((size_t)B * NI * 4);

    k_hash<<<512, 256, 0, stream>>>(q, rot, buckets);
    k_knorm<<<B * S / 4, 256, 0, stream>>>(k, kn);
    k_hist<<<B * CHB, 256, 0, stream>>>(buckets, counts);
    k_scan<<<B, NBT, 0, stream>>>(counts, base);
    k_scatter<<<B * CHB, 256, 0, stream>>>(buckets, counts, base, stflat, sbkt, undo);
    k_loc<<<B * NI / 256, 256, 0, stream>>>(buckets, undo, loc1);
    k_attn<<<B * NCH, 512, 0, stream>>>(q, kn, v, stflat, sbkt, loc1, so, slog);
    k_comb<<<B * S / 4, 256, 0, stream>>>(undo, slog, so, out);
}

// Round 2
// 132.244 us; speedup vs baseline: 2.2429x; 2.2429x over previous
//
#include <hip/hip_runtime.h>
#include <hip/hip_bf16.h>
#include <math.h>

// ---- problem constants (fixed by setup_inputs) ----
constexpr int B   = 4;
constexpr int S   = 4096;
constexpr int D   = 64;
constexpr int NH  = 8;        // hash rounds
constexpr int NB  = 64;       // buckets per hash
constexpr int NBT = 512;      // total buckets = NH*NB
constexpr int NI  = NH * S;   // items per batch = 32768
constexpr int NCH = 512;      // chunks per batch (of 64)
constexpr int CHB = 128;      // sort chunks per batch (of 256)

typedef __attribute__((ext_vector_type(8))) short bf16x8;
typedef __attribute__((ext_vector_type(4))) float f32x4;

__device__ __forceinline__ unsigned short bf_rne(float x) {
    unsigned u = __float_as_uint(x);
    u += 0x7fffu + ((u >> 16) & 1u);
    return (unsigned short)(u >> 16);
}
__device__ __forceinline__ float bf_tof(unsigned short h) {
    return __uint_as_float(((unsigned)h) << 16);
}

// ============================================================
// K1: LSH hashing — register-tiled small GEMM + argmax
// grid: B*NH*(S/128) = 1024 blocks, 256 threads
// thread: 4 tokens x 4 rotation-cols
// ============================================================
__global__ __launch_bounds__(256)
void k_hash(const float* __restrict__ q, const float* __restrict__ rot,
            int* __restrict__ buckets) {
    int blk = blockIdx.x;
    int tko = blk & 31, h = (blk >> 5) & 7, b = blk >> 8;
    __shared__ __align__(16) float rs[64 * 36];   // [d][n] padded
    for (int i = threadIdx.x; i < 2048; i += 256) {
        int nn = i & 31, d = i >> 5;
        rs[d * 36 + nn] = rot[(d * 8 + h) * 32 + nn];
    }
    __syncthreads();
    int tid = threadIdx.x;
    int ng = tid & 7, tg = tid >> 3;
    int t0 = tko * 128 + tg * 4;
    const float* qp = q + ((size_t)b * S + t0) * 64;
    float acc[4][4] = {};
    #pragma unroll 4
    for (int d4 = 0; d4 < 16; ++d4) {
        f32x4 r4[4];
        #pragma unroll
        for (int dd = 0; dd < 4; ++dd)
            r4[dd] = *(const f32x4*)(rs + (4 * d4 + dd) * 36 + 4 * ng);
        #pragma unroll
        for (int i = 0; i < 4; ++i) {
            f32x4 q4 = *(const f32x4*)(qp + i * 64 + d4 * 4);
            #pragma unroll
            for (int dd = 0; dd < 4; ++dd)
                #pragma unroll
                for (int c = 0; c < 4; ++c)
                    acc[i][c] += q4[dd] * r4[dd][c];
        }
    }
    #pragma unroll
    for (int i = 0; i < 4; ++i) {
        float vp = -3.402823466e38f, vn = -3.402823466e38f;
        int ip = 0, in_ = 0;
        #pragma unroll
        for (int c = 0; c < 4; ++c) {
            float a = acc[i][c]; int idx = 4 * ng + c;
            if (a > vp)  { vp = a;  ip = idx; }
            if (-a > vn) { vn = -a; in_ = idx; }
        }
        #pragma unroll
        for (int off = 1; off < 8; off <<= 1) {
            float ov = __shfl_xor(vp, off); int oi = __shfl_xor(ip, off);
            if (ov > vp || (ov == vp && oi < ip)) { vp = ov; ip = oi; }
            ov = __shfl_xor(vn, off); oi = __shfl_xor(in_, off);
            if (ov > vn || (ov == vn && oi < in_)) { vn = ov; in_ = oi; }
        }
        if (ng == 0) {
            int bi = (vn > vp) ? (in_ + 32) : ip;   // tie -> positive half
            buckets[b * NI + h * 4096 + t0 + i] = bi + h * NB;
        }
    }
}

// ============================================================
// K1b: normalize k rows
// ============================================================
__global__ void k_knorm(const float* __restrict__ k, float* __restrict__ kn) {
    int row  = blockIdx.x * 4 + (threadIdx.x >> 6);
    int lane = threadIdx.x & 63;
    float v = k[(size_t)row * D + lane];
    float ss = v * v;
#pragma unroll
    for (int m = 1; m < 64; m <<= 1) ss += __shfl_xor(ss, m, 64);
    kn[(size_t)row * D + lane] = v / sqrtf(ss);
}

// ============================================================
// K2: per-chunk bucket histograms (chunks of 256 items)
// ============================================================
__global__ void k_hist(const int* __restrict__ buckets, int* __restrict__ counts) {
    int b = blockIdx.x >> 7, c = blockIdx.x & 127;
    __shared__ int hist[NBT];
    hist[threadIdx.x] = 0; hist[threadIdx.x + 256] = 0;
    __syncthreads();
    int bkt = buckets[b * NI + c * 256 + threadIdx.x];
    atomicAdd(&hist[bkt], 1);
    __syncthreads();
    counts[(b * CHB + c) * NBT + threadIdx.x]       = hist[threadIdx.x];
    counts[(b * CHB + c) * NBT + threadIdx.x + 256] = hist[threadIdx.x + 256];
}

// ============================================================
// K3a: per-(b,bucket) scan over 128 chunks (wave scan)
// grid: B*NBT = 2048 blocks, 64 threads
// ============================================================
__global__ void k_scan1(int* __restrict__ counts, int* __restrict__ tot) {
    int bkt = blockIdx.x & 511, b = blockIdx.x >> 9;
    int lane = threadIdx.x;
    int i0 = (b * CHB + 2 * lane) * NBT + bkt;
    int v0 = counts[i0], v1 = counts[i0 + NBT];
    int s = v0 + v1;
    #pragma unroll
    for (int off = 1; off < 64; off <<= 1) {
        int t = __shfl_up(s, off);
        if (lane >= off) s += t;
    }
    int excl = s - v0 - v1;
    counts[i0] = excl;
    counts[i0 + NBT] = excl + v0;
    if (lane == 63) tot[b * NBT + bkt] = s;
}

// ============================================================
// K3b: cross-bucket exclusive scan (per batch)
// ============================================================
__global__ void k_scan2(const int* __restrict__ tot, int* __restrict__ base) {
    int b = blockIdx.x, bkt = threadIdx.x;
    __shared__ int bufA[NBT], bufB[NBT];
    int run = tot[b * NBT + bkt];
    bufA[bkt] = run;
    __syncthreads();
    int* src = bufA; int* dst = bufB;
    for (int off = 1; off < NBT; off <<= 1) {
        int x = src[bkt] + ((bkt >= off) ? src[bkt - off] : 0);
        dst[bkt] = x;
        __syncthreads();
        int* tsw = src; src = dst; dst = tsw;
    }
    base[b * NBT + bkt] = src[bkt] - run;
}

// ============================================================
// K4: stable scatter — packed sorted meta + inverse permutation
// ============================================================
__global__ void k_scatter(const int* __restrict__ buckets, const int* __restrict__ counts,
                          const int* __restrict__ base, int* __restrict__ spos,
                          int* __restrict__ undo) {
    int b = blockIdx.x >> 7, c = blockIdx.x & 127;
    __shared__ int bk_s[256];
    int i_loc  = threadIdx.x;
    int i_flat = c * 256 + i_loc;
    int bkt = buckets[b * NI + i_flat];
    bk_s[i_loc] = bkt;
    __syncthreads();
    int rank = 0;
    for (int j = 0; j < 256; ++j) {
        int vv = bk_s[j];
        rank += (j < i_loc && vv == bkt);
    }
    int pos = base[b * NBT + bkt] + counts[(b * CHB + c) * NBT + bkt] + rank;
    spos[b * NI + pos] = (i_flat & 4095) | (bkt << 12);   // t | bkt<<12
    undo[b * NI + i_flat] = pos;
}

// ============================================================
// K5: transposed loc table: locsT[(b*4096+t)*8 + h] = bkt*512 + chunk
// ============================================================
__global__ void k_locT(const int* __restrict__ buckets, const int* __restrict__ undo,
                       int* __restrict__ locsT) {
    int idx = blockIdx.x * 256 + threadIdx.x;   // B*NI total
    int b = idx >> 15; int r = idx & 32767; int h = r >> 12; int t = r & 4095;
    int l1 = buckets[idx] * NCH + (undo[idx] >> 6);
    locsT[(((size_t)b << 12) | t) * 8 + h] = l1;
}

// ============================================================
// K6: chunked attention via MFMA (64 q rows x 128 keys, d=64)
//   dots: single-bf16; PV: split-bf16 (ph*vh + pl*vh + ph*vl)
//   block = 256 threads = 4 waves; wave w owns rows 16w..16w+15
// ============================================================
__global__ __launch_bounds__(256, 2)
void k_attn(const float* __restrict__ q, const float* __restrict__ kn,
            const float* __restrict__ v, const int* __restrict__ spos,
            const int* __restrict__ locsT, float* __restrict__ so,
            float* __restrict__ slog) {
    int n = blockIdx.x & 511, b = blockIdx.x >> 9;
    __shared__ __align__(16) char buf[63232];
    unsigned short* qs = (unsigned short*)buf;            // [64][72] bf16 (q/8)
    unsigned short* ks = (unsigned short*)(buf + 9216);   // [128][72] bf16
    int* mq = (int*)(buf + 27648);                        // [64]  t|bkt<<12
    int* mk = (int*)(buf + 27904);                        // [128]
    unsigned short* ph = (unsigned short*)buf;            // [64][72] overlay (z-half)
    unsigned short* pl = (unsigned short*)(buf + 9216);   // [64][72] overlay
    unsigned short* vh = (unsigned short*)(buf + 28416);  // [64][136] v^T hi
    unsigned short* vl = (unsigned short*)(buf + 45824);  // [64][136] v^T lo

    int tid = threadIdx.x;
    size_t gb = (size_t)b * S * D;
    int bni = b * NI;

    // ---- phase A: sorted-position metadata ----
    if (tid < 64) mq[tid] = spos[bni + n * 64 + tid];
    else if (tid < 192) {
        int z = tid - 64;
        int nn = (z < 64) ? n : ((n + 511) & 511);   // z>=64: previous chunk
        mk[z] = spos[bni + nn * 64 + (z & 63)];
    }
    __syncthreads();

    // ---- phase B: stage tiles ----
    #pragma unroll
    for (int it = 0; it < 4; ++it) {                  // q (scaled by 1/8)
        int i = it * 256 + tid;
        int row = i >> 4, c4 = i & 15;
        int t = mq[row] & 4095;
        float4 f = *(const float4*)(q + gb + (size_t)t * 64 + c4 * 4);
        ushort4 o;
        o.x = bf_rne(f.x * 0.125f); o.y = bf_rne(f.y * 0.125f);
        o.z = bf_rne(f.z * 0.125f); o.w = bf_rne(f.w * 0.125f);
        *(ushort4*)(qs + row * 72 + c4 * 4) = o;
    }
    #pragma unroll
    for (int it = 0; it < 8; ++it) {                  // k (normalized)
        int i = it * 256 + tid;
        int row = i >> 4, c4 = i & 15;
        int t = mk[row] & 4095;
        float4 f = *(const float4*)(kn + gb + (size_t)t * 64 + c4 * 4);
        ushort4 o;
        o.x = bf_rne(f.x); o.y = bf_rne(f.y); o.z = bf_rne(f.z); o.w = bf_rne(f.w);
        *(ushort4*)(ks + row * 72 + c4 * 4) = o;
    }
    #pragma unroll
    for (int it = 0; it < 16; ++it) {                 // v transposed, hi/lo
        int i = it * 256 + tid;
        int d  = (i & 7) | (((i >> 8) & 7) << 3);
        int zp = ((i >> 3) & 31) | (((i >> 11) & 1) << 5);
        int t0 = mk[2 * zp] & 4095, t1 = mk[2 * zp + 1] & 4095;
        float f0 = v[gb + (size_t)t0 * 64 + d];
        float f1 = v[gb + (size_t)t1 * 64 + d];
        unsigned short h0 = bf_rne(f0), h1 = bf_rne(f1);
        *(unsigned*)(vh + d * 136 + 2 * zp) = (unsigned)h0 | ((unsigned)h1 << 16);
        unsigned short g0 = bf_rne(f0 - bf_tof(h0)), g1 = bf_rne(f1 - bf_tof(h1));
        *(unsigned*)(vl + d * 136 + 2 * zp) = (unsigned)g0 | ((unsigned)g1 << 16);
    }
    __syncthreads();

    int li = tid & 15, hi4 = (tid >> 4) & 3, w = tid >> 6;

    // ---- phase C: QK^T via MFMA ----
    f32x4 sacc[8];
    {
        bf16x8 a0 = *(bf16x8*)(qs + (16 * w + li) * 72 + 8 * hi4);
        bf16x8 a1 = *(bf16x8*)(qs + (16 * w + li) * 72 + 32 + 8 * hi4);
        #pragma unroll
        for (int zt = 0; zt < 8; ++zt) {
            bf16x8 b0 = *(bf16x8*)(ks + (16 * zt + li) * 72 + 8 * hi4);
            bf16x8 b1 = *(bf16x8*)(ks + (16 * zt + li) * 72 + 32 + 8 * hi4);
            f32x4 c = {0.f, 0.f, 0.f, 0.f};
            c = __builtin_amdgcn_mfma_f32_16x16x32_bf16(a0, b0, c, 0, 0, 0);
            c = __builtin_amdgcn_mfma_f32_16x16x32_bf16(a1, b1, c, 0, 0, 0);
            sacc[zt] = c;
        }
    }

    // ---- phase D: masks + dup correction + softmax (C-fragment layout) ----
    int tqr[4], bqr[4], lqr[4][8];
    #pragma unroll
    for (int j = 0; j < 4; ++j) {
        int R = 16 * w + 4 * hi4 + j;
        int m = mq[R];
        tqr[j] = m & 4095; bqr[j] = m >> 12;
        const int4* lp = (const int4*)(locsT + (((size_t)b << 12) | tqr[j]) * 8);
        int4 A = lp[0], Bv = lp[1];
        lqr[j][0] = A.x;  lqr[j][1] = A.y;  lqr[j][2] = A.z;  lqr[j][3] = A.w;
        lqr[j][4] = Bv.x; lqr[j][5] = Bv.y; lqr[j][6] = Bv.z; lqr[j][7] = Bv.w;
    }
    #pragma unroll
    for (int zt = 0; zt < 8; ++zt) {
        int z = 16 * zt + li;
        int mz = mk[z]; int tk = mz & 4095, bk = mz >> 12;
        const int4* lp = (const int4*)(locsT + (((size_t)b << 12) | tk) * 8);
        int4 A = lp[0], Bv = lp[1];
        int l1[8] = {A.x, A.y, A.z, A.w, Bv.x, Bv.y, Bv.z, Bv.w};
        int l2[8];
        #pragma unroll
        for (int h = 0; h < 8; ++h) l2[h] = (l1[h] & ~511) | ((l1[h] + 1) & 511);
        #pragma unroll
        for (int j = 0; j < 4; ++j) {
            float s = sacc[zt][j];
            if (tqr[j] == tk) s = -10000.0f;
            if (bqr[j] != bk) s = -3.402823466e38f;
            int dup = 0;
            #pragma unroll
            for (int h = 0; h < 8; ++h)
                dup += (int)(lqr[j][h] == l1[h]) + (int)(lqr[j][h] == l2[h]);
            s -= __logf((float)dup + 1e-9f);
            sacc[zt][j] = s;
        }
    }

    float inv[4], lse4[4];
    #pragma unroll
    for (int j = 0; j < 4; ++j) {
        float m = sacc[0][j];
        #pragma unroll
        for (int zt = 1; zt < 8; ++zt) m = fmaxf(m, sacc[zt][j]);
        #pragma unroll
        for (int off = 1; off < 16; off <<= 1) m = fmaxf(m, __shfl_xor(m, off));
        float sum = 0.f;
        #pragma unroll
        for (int zt = 0; zt < 8; ++zt) {
            float e = __expf(sacc[zt][j] - m);
            sacc[zt][j] = e; sum += e;
        }
        #pragma unroll
        for (int off = 1; off < 16; off <<= 1) sum += __shfl_xor(sum, off);
        lse4[j] = m + __logf(sum);
        inv[j] = 1.0f / sum;
    }
    if (li == 0) {
        #pragma unroll
        for (int j = 0; j < 4; ++j)
            slog[bni + n * 64 + 16 * w + 4 * hi4 + j] = lse4[j];
    }
    __syncthreads();   // all reads of qs/ks/mq/mk done before p overlays them

    // ---- phase E/F: P write (split bf16) + PV MFMA, in two z-halves ----
    f32x4 oacc[4] = {{0,0,0,0},{0,0,0,0},{0,0,0,0},{0,0,0,0}};
    #pragma unroll
    for (int half = 0; half < 2; ++half) {
        #pragma unroll
        for (int zt4 = 0; zt4 < 4; ++zt4) {
            int zt = half * 4 + zt4;
            #pragma unroll
            for (int j = 0; j < 4; ++j) {
                float p  = sacc[zt][j] * inv[j];
                float po = __shfl_xor(p, 1);
                if ((li & 1) == 0) {
                    int R  = 16 * w + 4 * hi4 + j;
                    int zl = 16 * zt4 + li;   // even
                    unsigned short h0 = bf_rne(p), h1 = bf_rne(po);
                    *(unsigned*)(ph + R * 72 + zl) = (unsigned)h0 | ((unsigned)h1 << 16);
                    unsigned short g0 = bf_rne(p - bf_tof(h0)), g1 = bf_rne(po - bf_tof(h1));
                    *(unsigned*)(pl + R * 72 + zl) = (unsigned)g0 | ((unsigned)g1 << 16);
                }
            }
        }
        __syncthreads();
        #pragma unroll
        for (int step = 0; step < 2; ++step) {
            bf16x8 pa = *(bf16x8*)(ph + (16 * w + li) * 72 + 32 * step + 8 * hi4);
            bf16x8 pb = *(bf16x8*)(pl + (16 * w + li) * 72 + 32 * step + 8 * hi4);
            #pragma unroll
            for (int nt = 0; nt < 4; ++nt) {
                bf16x8 vb = *(bf16x8*)(vh + (16 * nt + li) * 136 + 64 * half + 32 * step + 8 * hi4);
                bf16x8 vc = *(bf16x8*)(vl + (16 * nt + li) * 136 + 64 * half + 32 * step + 8 * hi4);
                oacc[nt] = __builtin_amdgcn_mfma_f32_16x16x32_bf16(pa, vb, oacc[nt], 0, 0, 0);
                oacc[nt] = __builtin_amdgcn_mfma_f32_16x16x32_bf16(pb, vb, oacc[nt], 0, 0, 0);
                oacc[nt] = __builtin_amdgcn_mfma_f32_16x16x32_bf16(pa, vc, oacc[nt], 0, 0, 0);
            }
        }
        __syncthreads();
    }

    // ---- epilogue ----
    size_t ob = ((size_t)bni + n * 64) * 64;
    #pragma unroll
    for (int nt = 0; nt < 4; ++nt)
        #pragma unroll
        for (int j = 0; j < 4; ++j)
            so[ob + (size_t)(16 * w + 4 * hi4 + j) * 64 + 16 * nt + li] = oacc[nt][j];
}

// ============================================================
// K7: unsort + combine across hash rounds
// ============================================================
__global__ void k_comb(const int* __restrict__ undo, const float* __restrict__ slog,
                       const float* __restrict__ so, float* __restrict__ out) {
    int flatT = blockIdx.x * 4 + (threadIdx.x >> 6);
    int lane  = threadIdx.x & 63;
    int b = flatT >> 12, t = flatT & (S - 1);
    int ph[NH]; float lg[NH];
    float m = -3.402823466e38f;
#pragma unroll
    for (int h = 0; h < NH; ++h) {
        ph[h] = undo[b * NI + (h << 12) + t];
        lg[h] = slog[b * NI + ph[h]];
        m = fmaxf(m, lg[h]);
    }
    float sum = 0.f;
#pragma unroll
    for (int h = 0; h < NH; ++h) sum += __expf(lg[h] - m);
    float lse2 = m + __logf(sum);
    float o = 0.f;
#pragma unroll
    for (int h = 0; h < NH; ++h) {
        float wgt = __expf(lg[h] - lse2);
        o += wgt * so[((size_t)b * NI + ph[h]) * D + lane];
    }
    out[(size_t)flatT * D + lane] = o;
}

// ============================================================
extern "C" void kernel_launch(void* const* d_in, const int* in_sizes, int n_in,
                              void* d_out, int out_size, void* d_ws, size_t ws_size,
                              hipStream_t stream) {
    const float* q   = (const float*)d_in[0];
    const float* k   = (const float*)d_in[1];
    const float* v   = (const float*)d_in[2];
    const float* rot = (const float*)d_in[3];
    float* out = (float*)d_out;

    char* ws = (char*)d_ws;
    size_t off = 0;
    auto alloc = [&](size_t bytes) -> void* {
        void* p = ws + off;
        off += (bytes + 255) & ~(size_t)255;
        return p;
    };
    float* kn      = (float*)alloc((size_t)B * S * D * 4);
    float* so      = (float*)alloc((size_t)B * NI * D * 4);
    float* slog    = (float*)alloc((size_t)B * NI * 4);
    int*   buckets = (int*)alloc((size_t)B * NI * 4);
    int*   counts  = (int*)alloc((size_t)B * CHB * NBT * 4);
    int*   tot     = (int*)alloc((size_t)B * NBT * 4);
    int*   base    = (int*)alloc((size_t)B * NBT * 4);
    int*   spos    = (int*)alloc((size_t)B * NI * 4);
    int*   undo    = (int*)alloc((size_t)B * NI * 4);
    int*   locsT   = (int*)alloc((size_t)B * S * NH * 4);

    k_hash<<<1024, 256, 0, stream>>>(q, rot, buckets);
    k_knorm<<<B * S / 4, 256, 0, stream>>>(k, kn);
    k_hist<<<B * CHB, 256, 0, stream>>>(buckets, counts);
    k_scan1<<<B * NBT, 64, 0, stream>>>(counts, tot);
    k_scan2<<<B, NBT, 0, stream>>>(tot, base);
    k_scatter<<<B * CHB, 256, 0, stream>>>(buckets, counts, base, spos, undo);
    k_locT<<<B * NI / 256, 256, 0, stream>>>(buckets, undo, locsT);
    k_attn<<<B * NCH, 256, 0, stream>>>(q, kn, v, spos, locsT, so, slog);
    k_comb<<<B * S / 4, 256, 0, stream>>>(undo, slog, so, out);
}